// Round 2
// baseline (721.740 us; speedup 1.0000x reference)
//
#include <hip/hip_runtime.h>
#include <stdint.h>

#define NB_    20000
#define CB_    128
#define EE_    320000
#define BN_    40000            // B*N
#define BE_    640000           // B*E
#define ETOT_  680000           // BE_ + BN_

typedef __attribute__((ext_vector_type(4))) float f4;
typedef __attribute__((ext_vector_type(4))) unsigned short us4;
typedef __attribute__((ext_vector_type(4))) unsigned int ui4;
typedef __attribute__((ext_vector_type(8))) __bf16 bf16x8;

static __device__ __forceinline__ unsigned short f2bf(float f){
    union { float f; unsigned int u; } v; v.f = f;
    unsigned int u = v.u;
    u += 0x7FFFu + ((u >> 16) & 1u);
    return (unsigned short)(u >> 16);
}
static __device__ __forceinline__ float bf2f(unsigned short b){
    union { unsigned int u; float f; } v; v.u = ((unsigned int)b) << 16;
    return v.f;
}
static __device__ __forceinline__ float sigf(float x){ return 1.f/(1.f+__expf(-x)); }
static __device__ __forceinline__ float tanhfast(float x){ return 2.f/(1.f+__expf(-2.f*x)) - 1.f; }
// async global->LDS DMA, 16B per lane, LDS dest = wave-uniform base + lane*16
static __device__ __forceinline__ void gl_lds16(const void* g, void* l){
    __builtin_amdgcn_global_load_lds((const __attribute__((address_space(1))) void*)g,
                                     (__attribute__((address_space(3))) void*)l, 16, 0, 0);
}

// ---------------- small pack kernels ----------------
__global__ void w2_kernel(const float* __restrict__ lew, const float* __restrict__ ae,
                          float* __restrict__ W2){
    int t = threadIdx.x;            // 64 threads: d=t>>2, h=t&3
    int d = t >> 2, h = t & 3;
    float s = 0.f;
    for (int c = 0; c < 64; ++c) s += lew[d*256 + h*64 + c] * ae[h*64 + c];
    W2[d*4 + h] = s;
}

__global__ void pack_linwT_kernel(const float* __restrict__ lw, unsigned short* __restrict__ wt){
    int tid = blockIdx.x*256 + threadIdx.x;   // 32768
    int n = tid >> 7, k = tid & 127;
    wt[n*128 + k] = f2bf(lw[k*256 + n]);
}

__global__ void pack_lstmw_kernel(const float* __restrict__ w_ih, unsigned short* __restrict__ Bp){
    int tid = blockIdx.x*256 + threadIdx.x;   // 589824 = 3*768*256
    int l   = tid / 196608;
    int rem = tid - l*196608;
    int p = rem >> 8, k = rem & 255;
    int jb = p / 192, q2 = p - jb*192;
    int chunk = q2 / 48, r = q2 - chunk*48;
    int gate = r >> 4, jj = r & 15;
    int gor = (gate == 0) ? 0 : (gate == 1 ? 2 : 3);   // i,g,o -> rows of i,f,g,o
    int srcrow = gor*256 + jb*64 + chunk*16 + jj;
    Bp[tid] = f2bf(w_ih[(l*1024 + srcrow)*256 + k]);
}

__global__ void pack_bias_kernel(const float* __restrict__ b_ih, const float* __restrict__ b_hh,
                                 float* __restrict__ bp){
    int tid = blockIdx.x*256 + threadIdx.x;
    if (tid >= 2304) return;
    int l = tid / 768, p = tid - l*768;
    int jb = p / 192, q2 = p - jb*192;
    int chunk = q2 / 48, r = q2 - chunk*48;
    int gate = r >> 4, jj = r & 15;
    int gor = (gate == 0) ? 0 : (gate == 1 ? 2 : 3);
    int srcrow = gor*256 + jb*64 + chunk*16 + jj;
    bp[tid] = b_ih[l*1024 + srcrow] + b_hh[l*1024 + srcrow];
}

// ---------------- GEMM1: xt[40000,256] = x[40000,128] @ lin_w  (bf16 MFMA) ----------------
__global__ __launch_bounds__(256) void gemm1_kernel(const float* __restrict__ x,
        const unsigned short* __restrict__ wt, unsigned short* __restrict__ xt){
    __shared__ unsigned short As[64*72];
    __shared__ unsigned short Bs[64*72];
    const int tid = threadIdx.x;
    const int bm = blockIdx.x, bn = blockIdx.y;
    const int lane = tid & 63, w = tid >> 6;
    const int wm = w & 1, wn = w >> 1;
    const int nl = lane & 15, q = lane >> 4;
    f4 acc[2][2] = {};
    for (int kc = 0; kc < 128; kc += 64) {
        #pragma unroll
        for (int it = 0; it < 4; ++it) {
            int s = tid + it*256;          // 1024 slots: 64 rows x 16 chunks of 4 floats
            int row = s >> 4, c4 = s & 15;
            f4 v = *(const f4*)&x[(bm*64+row)*128 + kc + c4*4];
            us4 o; o[0]=f2bf(v[0]); o[1]=f2bf(v[1]); o[2]=f2bf(v[2]); o[3]=f2bf(v[3]);
            *(us4*)&As[row*72 + c4*4] = o;
        }
        #pragma unroll
        for (int it = 0; it < 2; ++it) {
            int s = tid + it*256;          // 512 slots: 64 rows x 8 chunks of 8 bf16
            int row = s >> 3, c = s & 7;
            *(ui4*)&Bs[row*72 + c*8] = *(const ui4*)&wt[(bn*64+row)*128 + kc + c*8];
        }
        __syncthreads();
        #pragma unroll
        for (int kk = 0; kk < 64; kk += 32) {
            bf16x8 a[2], b[2];
            #pragma unroll
            for (int mt = 0; mt < 2; ++mt) a[mt] = *(const bf16x8*)&As[(wm*32 + mt*16 + nl)*72 + kk + q*8];
            #pragma unroll
            for (int nt = 0; nt < 2; ++nt) b[nt] = *(const bf16x8*)&Bs[(wn*32 + nt*16 + nl)*72 + kk + q*8];
            #pragma unroll
            for (int mt = 0; mt < 2; ++mt)
                #pragma unroll
                for (int nt = 0; nt < 2; ++nt)
                    acc[mt][nt] = __builtin_amdgcn_mfma_f32_16x16x32_bf16(a[mt], b[nt], acc[mt][nt], 0, 0, 0);
        }
        __syncthreads();
    }
    #pragma unroll
    for (int mt = 0; mt < 2; ++mt)
        #pragma unroll
        for (int nt = 0; nt < 2; ++nt)
            #pragma unroll
            for (int r = 0; r < 4; ++r) {
                int row = bm*64 + wm*32 + mt*16 + q*4 + r;
                int col = bn*64 + wn*32 + nt*16 + nl;
                xt[row*256 + col] = f2bf(acc[mt][nt][r]);
            }
}

// ---------------- per-node attention scores ----------------
__global__ __launch_bounds__(256) void scores_kernel(const unsigned short* __restrict__ xt,
        const float* __restrict__ att_src, const float* __restrict__ att_dst,
        float* __restrict__ s_src, float* __restrict__ s_dst){
    int n = blockIdx.x*4 + (threadIdx.x >> 6);
    int lane = threadIdx.x & 63;
    us4 xv = *(const us4*)&xt[n*256 + lane*4];
    f4 as = *(const f4*)&att_src[lane*4];
    f4 ad = *(const f4*)&att_dst[lane*4];
    float x0=bf2f(xv[0]), x1=bf2f(xv[1]), x2=bf2f(xv[2]), x3=bf2f(xv[3]);
    float ps = x0*as[0]+x1*as[1]+x2*as[2]+x3*as[3];
    float pd = x0*ad[0]+x1*ad[1]+x2*ad[2]+x3*ad[3];
    #pragma unroll
    for (int o = 1; o < 16; o <<= 1) { ps += __shfl_xor(ps, o, 64); pd += __shfl_xor(pd, o, 64); }
    if ((lane & 15) == 0) {
        s_src[n*4 + (lane>>4)] = ps;
        s_dst[n*4 + (lane>>4)] = pd;
    }
}

// ---------------- edge scores: esc[E,4] = edge_attr[E,16] @ W2[16,4] ----------------
__global__ __launch_bounds__(256) void eascore_kernel(const float* __restrict__ ea,
        const float* __restrict__ W2, float* __restrict__ esc){
    __shared__ float w2s[64];
    if (threadIdx.x < 64) w2s[threadIdx.x] = W2[threadIdx.x];
    __syncthreads();
    int e = blockIdx.x*256 + threadIdx.x;
    if (e >= EE_) return;
    f4 acc = {};
    #pragma unroll
    for (int d = 0; d < 16; ++d) {
        float v = ea[e*16 + d];
        f4 wv = *(const f4*)&w2s[d*4];
        acc += v * wv;
    }
    *(f4*)&esc[e*4] = acc;
}

// ---------------- CSR build ----------------
__global__ __launch_bounds__(256) void deghist_kernel(const int* __restrict__ ei, int* __restrict__ deg){
    int e = blockIdx.x*256 + threadIdx.x;
    if (e >= ETOT_) return;
    int dst;
    if (e < BE_) { int b = e / EE_, ee = e - b*EE_; dst = ei[EE_ + ee] + b*NB_; }
    else dst = e - BE_;
    atomicAdd(&deg[dst], 1);
}

__global__ __launch_bounds__(256) void scan1_kernel(const int* __restrict__ deg,
        int* __restrict__ inc, int* __restrict__ bsum){
    __shared__ int sd[256];
    int t = threadIdx.x, i = blockIdx.x*256 + t;
    int v = (i < BN_) ? deg[i] : 0;
    sd[t] = v; __syncthreads();
    #pragma unroll
    for (int d = 1; d < 256; d <<= 1) {
        int x = (t >= d) ? sd[t-d] : 0; __syncthreads();
        sd[t] += x; __syncthreads();
    }
    inc[i] = sd[t];
    if (t == 255) bsum[blockIdx.x] = sd[255];
}

__global__ __launch_bounds__(256) void scan2_kernel(const int* __restrict__ bsum,
        int* __restrict__ bpre, int nb){
    __shared__ int sd[256];
    int t = threadIdx.x;
    int v = (t < nb) ? bsum[t] : 0;
    sd[t] = v; __syncthreads();
    #pragma unroll
    for (int d = 1; d < 256; d <<= 1) {
        int x = (t >= d) ? sd[t-d] : 0; __syncthreads();
        sd[t] += x; __syncthreads();
    }
    if (t < nb) bpre[t] = sd[t] - v;
}

__global__ __launch_bounds__(256) void scan3_kernel(const int* __restrict__ inc,
        const int* __restrict__ deg, const int* __restrict__ bpre,
        int* __restrict__ offs, int* __restrict__ cur){
    int i = blockIdx.x*256 + threadIdx.x;
    if (i >= BN_) return;
    int o = inc[i] - deg[i] + bpre[blockIdx.x];
    offs[i] = o; cur[i] = o;
}

// ---------------- scatter: store exp(leakyrelu(score)), accumulate softmax denom ----------------
// max-subtraction dropped: scores ~ N(0, 1.4^2), extreme ~8 -> exp safe in fp32;
// normalization exp(a)/sum(exp(a)) is mathematically identical to the max-shifted form.
__global__ __launch_bounds__(256) void scatter_kernel(const int* __restrict__ ei,
        const float* __restrict__ s_src, const float* __restrict__ s_dst,
        const float* __restrict__ esc, int* __restrict__ cur,
        int* __restrict__ csr_src, float* __restrict__ csr_e, float* __restrict__ ssum){
    int e = blockIdx.x*256 + threadIdx.x;
    if (e >= ETOT_) return;
    int src, dst; f4 a;
    if (e < BE_) {
        int b = e / EE_, ee = e - b*EE_;
        src = ei[ee] + b*NB_;
        dst = ei[EE_ + ee] + b*NB_;
        a = *(const f4*)&esc[ee*4];
    } else {
        src = dst = e - BE_;
        a = (f4){0.f, 0.f, 0.f, 0.f};
    }
    a += *(const f4*)&s_src[src*4];
    a += *(const f4*)&s_dst[dst*4];
    f4 ev;
    #pragma unroll
    for (int h = 0; h < 4; ++h) {
        float v = (a[h] > 0.f) ? a[h] : 0.2f*a[h];
        ev[h] = __expf(v);
    }
    int pos = atomicAdd(&cur[dst], 1);
    csr_src[pos] = src;
    *(f4*)&csr_e[pos*4] = ev;
    atomicAdd(&ssum[dst*4 + 0], ev[0]);
    atomicAdd(&ssum[dst*4 + 1], ev[1]);
    atomicAdd(&ssum[dst*4 + 2], ev[2]);
    atomicAdd(&ssum[dst*4 + 3], ev[3]);
}

// ---------------- aggregate: single gather pass, 4-wide MLP unroll ----------------
__global__ __launch_bounds__(256) void aggregate_kernel(const int* __restrict__ offs,
        const int* __restrict__ deg, const int* __restrict__ csr_src,
        const float* __restrict__ csr_e, const float* __restrict__ ssum,
        const unsigned short* __restrict__ xt,
        const float* __restrict__ gat_bias, unsigned short* __restrict__ spat){
    int n = blockIdx.x*4 + (threadIdx.x >> 6);
    int lane = threadIdx.x & 63;
    int start = offs[n], d = deg[n];
    int h = lane >> 4;
    float sh = ssum[n*4 + h];
    f4 accv = {};
    for (int base = 0; base < d; base += 64) {
        int cnt = min(64, d - base);
        int idx0 = start + base;
        int srcl = (base + lane < d) ? csr_src[idx0 + lane] : 0;
        int i = 0;
        for (; i + 4 <= cnt; i += 4) {
            int s0 = __shfl(srcl, i,   64);
            int s1 = __shfl(srcl, i+1, 64);
            int s2 = __shfl(srcl, i+2, 64);
            int s3 = __shfl(srcl, i+3, 64);
            float e0 = csr_e[(idx0+i  )*4 + h];
            float e1 = csr_e[(idx0+i+1)*4 + h];
            float e2 = csr_e[(idx0+i+2)*4 + h];
            float e3 = csr_e[(idx0+i+3)*4 + h];
            us4 x0 = *(const us4*)&xt[s0*256 + lane*4];
            us4 x1 = *(const us4*)&xt[s1*256 + lane*4];
            us4 x2 = *(const us4*)&xt[s2*256 + lane*4];
            us4 x3 = *(const us4*)&xt[s3*256 + lane*4];
            #pragma unroll
            for (int c = 0; c < 4; ++c)
                accv[c] += e0*bf2f(x0[c]) + e1*bf2f(x1[c]) + e2*bf2f(x2[c]) + e3*bf2f(x3[c]);
        }
        for (; i < cnt; ++i) {
            int s0 = __shfl(srcl, i, 64);
            float e0 = csr_e[(idx0+i)*4 + h];
            us4 x0 = *(const us4*)&xt[s0*256 + lane*4];
            #pragma unroll
            for (int c = 0; c < 4; ++c) accv[c] += e0*bf2f(x0[c]);
        }
    }
    float invs = 1.f / (sh + 1e-16f);
    f4 gb = *(const f4*)&gat_bias[lane*4];
    accv = accv * invs + gb;
    us4 o4; o4[0]=f2bf(accv[0]); o4[1]=f2bf(accv[1]); o4[2]=f2bf(accv[2]); o4[3]=f2bf(accv[3]);
    *(us4*)&spat[n*256 + lane*4] = o4;
}

// ---------------- LSTM layer: global_load_lds staging + XOR-swizzled LDS (T2/rule#21) ----------------
// LDS tiles linear [rows][64] bf16 (128B rows). LDS(row, bcol) holds global(row, bcol ^ ((row&7)<<4)):
// DMA writes linearly (base + lane*16); the inverse swizzle is applied to the per-lane GLOBAL source;
// ds_read applies the same XOR. Per 16-lane phase the 8 16B slots are each hit exactly twice -> 2-way
// aliasing = free (m136).
__global__ __launch_bounds__(256) void lstm_kernel(const unsigned short* __restrict__ A,
        const unsigned short* __restrict__ Bp, const float* __restrict__ bias,
        float* __restrict__ hs_out, float* __restrict__ cs_out, unsigned short* __restrict__ hnext){
    __shared__ unsigned short As[64*64];    // 8 KB
    __shared__ unsigned short Bs[192*64];   // 24 KB
    const int tid = threadIdx.x;
    const int bm = blockIdx.x, jb = blockIdx.y;
    const int lane = tid & 63, w = tid >> 6;
    const int nl = lane & 15, q = lane >> 4;
    const int rsub = lane >> 3, csub = lane & 7;
    const int swz = ((csub ^ rsub) << 4);   // byte offset of this lane's 16B block within a 128B row
    f4 acc[4][3] = {};
    // per-lane global base addresses (row = +rsub, col-block pre-swizzled)
    const char* Ab = (const char*)A + ((size_t)(bm*64 + rsub))*512 + swz;        // A row = 512B
    const char* Bb = (const char*)(Bp + (size_t)jb*192*256) + (size_t)rsub*512 + swz;
    for (int kc = 0; kc < 256; kc += 64) {
        // wave w stages: A insts t=2w..2w+1 (rows t*8..t*8+7), B insts t=6w..6w+5
        #pragma unroll
        for (int i = 0; i < 2; ++i) {
            int t = 2*w + i;
            gl_lds16(Ab + (size_t)t*4096 + kc*2, (char*)As + t*1024);
        }
        #pragma unroll
        for (int i = 0; i < 6; ++i) {
            int t = 6*w + i;
            gl_lds16(Bb + (size_t)t*4096 + kc*2, (char*)Bs + t*1024);
        }
        __syncthreads();   // compiler emits s_waitcnt vmcnt(0) before s_barrier -> DMA complete
        #pragma unroll
        for (int kk = 0; kk < 64; kk += 32) {
            const int cswz = (kk*2 + q*16) ^ ((nl & 7) << 4);
            bf16x8 a[4], b[3];
            #pragma unroll
            for (int mt = 0; mt < 4; ++mt)
                a[mt] = *(const bf16x8*)((const char*)As + (mt*16 + nl)*128 + cswz);
            #pragma unroll
            for (int gt = 0; gt < 3; ++gt)
                b[gt] = *(const bf16x8*)((const char*)Bs + (w*48 + gt*16 + nl)*128 + cswz);
            #pragma unroll
            for (int mt = 0; mt < 4; ++mt)
                #pragma unroll
                for (int gt = 0; gt < 3; ++gt)
                    acc[mt][gt] = __builtin_amdgcn_mfma_f32_16x16x32_bf16(a[mt], b[gt], acc[mt][gt], 0, 0, 0);
        }
        __syncthreads();
    }
    const int j = jb*64 + w*16 + nl;
    const float bi = bias[jb*192 + w*48 +  0 + nl];
    const float bg = bias[jb*192 + w*48 + 16 + nl];
    const float bo = bias[jb*192 + w*48 + 32 + nl];
    #pragma unroll
    for (int mt = 0; mt < 4; ++mt)
        #pragma unroll
        for (int r = 0; r < 4; ++r) {
            int m = bm*64 + mt*16 + q*4 + r;
            float iv = acc[mt][0][r] + bi;
            float gv = acc[mt][1][r] + bg;
            float ov = acc[mt][2][r] + bo;
            float c = sigf(iv) * tanhfast(gv);
            float hh = sigf(ov) * tanhfast(c);
            cs_out[m*256 + j] = c;
            hs_out[m*256 + j] = hh;
            if (hnext) hnext[m*256 + j] = f2bf(hh);
        }
}

// ---------------- LayerNorm ----------------
__global__ __launch_bounds__(256) void ln_kernel(const float* __restrict__ hin,
        const float* __restrict__ g, const float* __restrict__ b, float* __restrict__ out){
    int n = blockIdx.x*4 + (threadIdx.x >> 6);
    int lane = threadIdx.x & 63;
    f4 v = *(const f4*)&hin[n*256 + lane*4];
    float s = v[0]+v[1]+v[2]+v[3];
    float ss = v[0]*v[0]+v[1]*v[1]+v[2]*v[2]+v[3]*v[3];
    #pragma unroll
    for (int o = 1; o < 64; o <<= 1) { s += __shfl_xor(s,o,64); ss += __shfl_xor(ss,o,64); }
    float mu = s * (1.f/256.f);
    float var = ss * (1.f/256.f) - mu*mu;
    float rstd = rsqrtf(var + 1e-5f);
    f4 gg = *(const f4*)&g[lane*4], bb = *(const f4*)&b[lane*4];
    f4 o4 = (v - mu) * rstd * gg + bb;
    *(f4*)&out[n*256 + lane*4] = o4;
}

// ---------------- host ----------------
static inline char* carve(char*& p, size_t bytes){
    char* r = p; p += (bytes + 255) & ~(size_t)255; return r;
}

extern "C" void kernel_launch(void* const* d_in, const int* in_sizes, int n_in,
                              void* d_out, int out_size, void* d_ws, size_t ws_size,
                              hipStream_t stream){
    const float* x         = (const float*)d_in[0];
    const int*   ei        = (const int*)  d_in[1];
    const float* edge_attr = (const float*)d_in[2];
    const float* lin_w     = (const float*)d_in[3];
    const float* att_src   = (const float*)d_in[4];
    const float* att_dst   = (const float*)d_in[5];
    const float* lin_edge_w= (const float*)d_in[6];
    const float* att_edge  = (const float*)d_in[7];
    const float* gat_bias  = (const float*)d_in[8];
    const float* w_ih      = (const float*)d_in[9];
    const float* b_ih      = (const float*)d_in[11];
    const float* b_hh      = (const float*)d_in[12];
    const float* ln_g      = (const float*)d_in[13];
    const float* ln_b      = (const float*)d_in[14];

    float* out = (float*)d_out;
    float* hs_base = out + 10240000;          // [3][40000][256]
    float* cs_base = out + 40960000;          // [3][40000][256]

    // scratch aliased into d_out (liveness verified: each region is dead before
    // the kernel that writes its final contents runs)
    unsigned short* xt   = (unsigned short*)(out + 0);          // dead after aggregate
    float* ssum          = out + 5120000;                        // gap after xt, dead after aggregate
    float* esc           = out + 10240000;                       // dead before layer0 writes hs[0]
    int*   csr_src       = (int*)(out + 40960000);               // dead before layer0 writes cs[0]
    float* csr_e         = out + 41640000;                       // ditto
    unsigned short* spat = (unsigned short*)(out + 51200000);    // in cs[1], dead before layer1
    unsigned short* h0   = (unsigned short*)(out + 61440000);    // in cs[2], dead before layer2
    unsigned short* h1   = (unsigned short*)(out + 0);           // reuse xt region

    char* p = (char*)d_ws;
    float* W2          = (float*)carve(p, 64*4);
    float* s_src       = (float*)carve(p, (size_t)BN_*4*4);
    float* s_dst       = (float*)carve(p, (size_t)BN_*4*4);
    unsigned short* lwT= (unsigned short*)carve(p, 32768*2);
    unsigned short* Bp = (unsigned short*)carve(p, 589824*2);
    float* biasP       = (float*)carve(p, 2304*4);
    int* deg           = (int*)carve(p, BN_*4);
    int* inc           = (int*)carve(p, 157*256*4);
    int* bsum          = (int*)carve(p, 256*4);
    int* bpre          = (int*)carve(p, 256*4);
    int* offs          = (int*)carve(p, BN_*4);
    int* cur           = (int*)carve(p, BN_*4);

    hipMemsetAsync(deg, 0, BN_*4, stream);
    hipMemsetAsync(ssum, 0, (size_t)BN_*4*4, stream);
    w2_kernel<<<1, 64, 0, stream>>>(lin_edge_w, att_edge, W2);
    pack_linwT_kernel<<<128, 256, 0, stream>>>(lin_w, lwT);
    pack_lstmw_kernel<<<2304, 256, 0, stream>>>(w_ih, Bp);
    pack_bias_kernel<<<9, 256, 0, stream>>>(b_ih, b_hh, biasP);

    gemm1_kernel<<<dim3(625, 4), 256, 0, stream>>>(x, lwT, xt);
    scores_kernel<<<10000, 256, 0, stream>>>(xt, att_src, att_dst, s_src, s_dst);
    eascore_kernel<<<1250, 256, 0, stream>>>(edge_attr, W2, esc);

    deghist_kernel<<<2657, 256, 0, stream>>>(ei, deg);
    scan1_kernel<<<157, 256, 0, stream>>>(deg, inc, bsum);
    scan2_kernel<<<1, 256, 0, stream>>>(bsum, bpre, 157);
    scan3_kernel<<<157, 256, 0, stream>>>(inc, deg, bpre, offs, cur);
    scatter_kernel<<<2657, 256, 0, stream>>>(ei, s_src, s_dst, esc, cur, csr_src, csr_e, ssum);
    aggregate_kernel<<<10000, 256, 0, stream>>>(offs, deg, csr_src, csr_e, ssum, xt, gat_bias, spat);

    lstm_kernel<<<dim3(625, 4), 256, 0, stream>>>(spat, Bp,          biasP,        hs_base,            cs_base,            h0);
    lstm_kernel<<<dim3(625, 4), 256, 0, stream>>>(h0,   Bp + 196608, biasP + 768,  hs_base + 10240000, cs_base + 10240000, h1);
    lstm_kernel<<<dim3(625, 4), 256, 0, stream>>>(h1,   Bp + 393216, biasP + 1536, hs_base + 20480000, cs_base + 20480000, (unsigned short*)nullptr);

    ln_kernel<<<10000, 256, 0, stream>>>(hs_base + 20480000, ln_g, ln_b, out);
}

// Round 3
// 600.177 us; speedup vs baseline: 1.2025x; 1.2025x over previous
//
#include <hip/hip_runtime.h>
#include <stdint.h>

#define NB_    20000
#define CB_    128
#define EE_    320000
#define BN_    40000            // B*N
#define BE_    640000           // B*E
#define ETOT_  680000           // BE_ + BN_

typedef __attribute__((ext_vector_type(4))) float f4;
typedef __attribute__((ext_vector_type(4))) unsigned short us4;
typedef __attribute__((ext_vector_type(4))) unsigned int ui4;
typedef __attribute__((ext_vector_type(8))) __bf16 bf16x8;

static __device__ __forceinline__ unsigned short f2bf(float f){
    union { float f; unsigned int u; } v; v.f = f;
    unsigned int u = v.u;
    u += 0x7FFFu + ((u >> 16) & 1u);
    return (unsigned short)(u >> 16);
}
static __device__ __forceinline__ float bf2f(unsigned short b){
    union { unsigned int u; float f; } v; v.u = ((unsigned int)b) << 16;
    return v.f;
}
static __device__ __forceinline__ float sigf(float x){ return 1.f/(1.f+__expf(-x)); }
static __device__ __forceinline__ float tanhfast(float x){ return 2.f/(1.f+__expf(-2.f*x)) - 1.f; }
static __device__ __forceinline__ f4 fmax4(f4 a, f4 b){
    f4 r; r[0]=fmaxf(a[0],b[0]); r[1]=fmaxf(a[1],b[1]); r[2]=fmaxf(a[2],b[2]); r[3]=fmaxf(a[3],b[3]); return r;
}
// async global->LDS DMA, 16B per lane, LDS dest = wave-uniform base + lane*16
static __device__ __forceinline__ void gl_lds16(const void* g, void* l){
    __builtin_amdgcn_global_load_lds((const __attribute__((address_space(1))) void*)g,
                                     (__attribute__((address_space(3))) void*)l, 16, 0, 0);
}

// ---------------- small pack kernels ----------------
__global__ void w2_kernel(const float* __restrict__ lew, const float* __restrict__ ae,
                          float* __restrict__ W2){
    int t = threadIdx.x;            // 64 threads: d=t>>2, h=t&3
    int d = t >> 2, h = t & 3;
    float s = 0.f;
    for (int c = 0; c < 64; ++c) s += lew[d*256 + h*64 + c] * ae[h*64 + c];
    W2[d*4 + h] = s;
}

__global__ void pack_linwT_kernel(const float* __restrict__ lw, unsigned short* __restrict__ wt){
    int tid = blockIdx.x*256 + threadIdx.x;   // 32768
    int n = tid >> 7, k = tid & 127;
    wt[n*128 + k] = f2bf(lw[k*256 + n]);
}

__global__ void pack_lstmw_kernel(const float* __restrict__ w_ih, unsigned short* __restrict__ Bp){
    int tid = blockIdx.x*256 + threadIdx.x;   // 589824 = 3*768*256
    int l   = tid / 196608;
    int rem = tid - l*196608;
    int p = rem >> 8, k = rem & 255;
    int jb = p / 192, q2 = p - jb*192;
    int chunk = q2 / 48, r = q2 - chunk*48;
    int gate = r >> 4, jj = r & 15;
    int gor = (gate == 0) ? 0 : (gate == 1 ? 2 : 3);   // i,g,o -> rows of i,f,g,o
    int srcrow = gor*256 + jb*64 + chunk*16 + jj;
    Bp[tid] = f2bf(w_ih[(l*1024 + srcrow)*256 + k]);
}

__global__ void pack_bias_kernel(const float* __restrict__ b_ih, const float* __restrict__ b_hh,
                                 float* __restrict__ bp){
    int tid = blockIdx.x*256 + threadIdx.x;
    if (tid >= 2304) return;
    int l = tid / 768, p = tid - l*768;
    int jb = p / 192, q2 = p - jb*192;
    int chunk = q2 / 48, r = q2 - chunk*48;
    int gate = r >> 4, jj = r & 15;
    int gor = (gate == 0) ? 0 : (gate == 1 ? 2 : 3);
    int srcrow = gor*256 + jb*64 + chunk*16 + jj;
    bp[tid] = b_ih[l*1024 + srcrow] + b_hh[l*1024 + srcrow];
}

// ---------------- GEMM1: xt[40000,256] = x[40000,128] @ lin_w  (bf16 MFMA) ----------------
__global__ __launch_bounds__(256) void gemm1_kernel(const float* __restrict__ x,
        const unsigned short* __restrict__ wt, unsigned short* __restrict__ xt){
    __shared__ unsigned short As[64*72];
    __shared__ unsigned short Bs[64*72];
    const int tid = threadIdx.x;
    const int bm = blockIdx.x, bn = blockIdx.y;
    const int lane = tid & 63, w = tid >> 6;
    const int wm = w & 1, wn = w >> 1;
    const int nl = lane & 15, q = lane >> 4;
    f4 acc[2][2] = {};
    for (int kc = 0; kc < 128; kc += 64) {
        #pragma unroll
        for (int it = 0; it < 4; ++it) {
            int s = tid + it*256;          // 1024 slots: 64 rows x 16 chunks of 4 floats
            int row = s >> 4, c4 = s & 15;
            f4 v = *(const f4*)&x[(bm*64+row)*128 + kc + c4*4];
            us4 o; o[0]=f2bf(v[0]); o[1]=f2bf(v[1]); o[2]=f2bf(v[2]); o[3]=f2bf(v[3]);
            *(us4*)&As[row*72 + c4*4] = o;
        }
        #pragma unroll
        for (int it = 0; it < 2; ++it) {
            int s = tid + it*256;          // 512 slots: 64 rows x 8 chunks of 8 bf16
            int row = s >> 3, c = s & 7;
            *(ui4*)&Bs[row*72 + c*8] = *(const ui4*)&wt[(bn*64+row)*128 + kc + c*8];
        }
        __syncthreads();
        #pragma unroll
        for (int kk = 0; kk < 64; kk += 32) {
            bf16x8 a[2], b[2];
            #pragma unroll
            for (int mt = 0; mt < 2; ++mt) a[mt] = *(const bf16x8*)&As[(wm*32 + mt*16 + nl)*72 + kk + q*8];
            #pragma unroll
            for (int nt = 0; nt < 2; ++nt) b[nt] = *(const bf16x8*)&Bs[(wn*32 + nt*16 + nl)*72 + kk + q*8];
            #pragma unroll
            for (int mt = 0; mt < 2; ++mt)
                #pragma unroll
                for (int nt = 0; nt < 2; ++nt)
                    acc[mt][nt] = __builtin_amdgcn_mfma_f32_16x16x32_bf16(a[mt], b[nt], acc[mt][nt], 0, 0, 0);
        }
        __syncthreads();
    }
    #pragma unroll
    for (int mt = 0; mt < 2; ++mt)
        #pragma unroll
        for (int nt = 0; nt < 2; ++nt)
            #pragma unroll
            for (int r = 0; r < 4; ++r) {
                int row = bm*64 + wm*32 + mt*16 + q*4 + r;
                int col = bn*64 + wn*32 + nt*16 + nl;
                xt[row*256 + col] = f2bf(acc[mt][nt][r]);
            }
}

// ---------------- per-node attention scores ----------------
__global__ __launch_bounds__(256) void scores_kernel(const unsigned short* __restrict__ xt,
        const float* __restrict__ att_src, const float* __restrict__ att_dst,
        float* __restrict__ s_src, float* __restrict__ s_dst){
    int n = blockIdx.x*4 + (threadIdx.x >> 6);
    int lane = threadIdx.x & 63;
    us4 xv = *(const us4*)&xt[n*256 + lane*4];
    f4 as = *(const f4*)&att_src[lane*4];
    f4 ad = *(const f4*)&att_dst[lane*4];
    float x0=bf2f(xv[0]), x1=bf2f(xv[1]), x2=bf2f(xv[2]), x3=bf2f(xv[3]);
    float ps = x0*as[0]+x1*as[1]+x2*as[2]+x3*as[3];
    float pd = x0*ad[0]+x1*ad[1]+x2*ad[2]+x3*ad[3];
    #pragma unroll
    for (int o = 1; o < 16; o <<= 1) { ps += __shfl_xor(ps, o, 64); pd += __shfl_xor(pd, o, 64); }
    if ((lane & 15) == 0) {
        s_src[n*4 + (lane>>4)] = ps;
        s_dst[n*4 + (lane>>4)] = pd;
    }
}

// ---------------- edge scores: esc[E,4] = edge_attr[E,16] @ W2[16,4] ----------------
__global__ __launch_bounds__(256) void eascore_kernel(const float* __restrict__ ea,
        const float* __restrict__ W2, float* __restrict__ esc){
    __shared__ float w2s[64];
    if (threadIdx.x < 64) w2s[threadIdx.x] = W2[threadIdx.x];
    __syncthreads();
    int e = blockIdx.x*256 + threadIdx.x;
    if (e >= EE_) return;
    f4 acc = {};
    #pragma unroll
    for (int d = 0; d < 16; ++d) {
        float v = ea[e*16 + d];
        f4 wv = *(const f4*)&w2s[d*4];
        acc += v * wv;
    }
    *(f4*)&esc[e*4] = acc;
}

// ---------------- CSR build ----------------
__global__ __launch_bounds__(256) void deghist_kernel(const int* __restrict__ ei, int* __restrict__ deg){
    int e = blockIdx.x*256 + threadIdx.x;
    if (e >= ETOT_) return;
    int dst;
    if (e < BE_) { int b = e / EE_, ee = e - b*EE_; dst = ei[EE_ + ee] + b*NB_; }
    else dst = e - BE_;
    atomicAdd(&deg[dst], 1);
}

__global__ __launch_bounds__(256) void scan1_kernel(const int* __restrict__ deg,
        int* __restrict__ inc, int* __restrict__ bsum){
    __shared__ int sd[256];
    int t = threadIdx.x, i = blockIdx.x*256 + t;
    int v = (i < BN_) ? deg[i] : 0;
    sd[t] = v; __syncthreads();
    #pragma unroll
    for (int d = 1; d < 256; d <<= 1) {
        int x = (t >= d) ? sd[t-d] : 0; __syncthreads();
        sd[t] += x; __syncthreads();
    }
    inc[i] = sd[t];
    if (t == 255) bsum[blockIdx.x] = sd[255];
}

__global__ __launch_bounds__(256) void scan2_kernel(const int* __restrict__ bsum,
        int* __restrict__ bpre, int nb){
    __shared__ int sd[256];
    int t = threadIdx.x;
    int v = (t < nb) ? bsum[t] : 0;
    sd[t] = v; __syncthreads();
    #pragma unroll
    for (int d = 1; d < 256; d <<= 1) {
        int x = (t >= d) ? sd[t-d] : 0; __syncthreads();
        sd[t] += x; __syncthreads();
    }
    if (t < nb) bpre[t] = sd[t] - v;
}

__global__ __launch_bounds__(256) void scan3_kernel(const int* __restrict__ inc,
        const int* __restrict__ deg, const int* __restrict__ bpre,
        int* __restrict__ offs, int* __restrict__ cur){
    int i = blockIdx.x*256 + threadIdx.x;
    if (i >= BN_) return;
    int o = inc[i] - deg[i] + bpre[blockIdx.x];
    offs[i] = o; cur[i] = o;
}

__global__ __launch_bounds__(256) void scatter_kernel(const int* __restrict__ ei,
        const float* __restrict__ s_src, const float* __restrict__ s_dst,
        const float* __restrict__ esc, int* __restrict__ cur,
        int* __restrict__ csr_src, float* __restrict__ csr_alpha){
    int e = blockIdx.x*256 + threadIdx.x;
    if (e >= ETOT_) return;
    int src, dst; f4 a;
    if (e < BE_) {
        int b = e / EE_, ee = e - b*EE_;
        src = ei[ee] + b*NB_;
        dst = ei[EE_ + ee] + b*NB_;
        a = *(const f4*)&esc[ee*4];
    } else {
        src = dst = e - BE_;
        a = (f4){0.f, 0.f, 0.f, 0.f};
    }
    a += *(const f4*)&s_src[src*4];
    a += *(const f4*)&s_dst[dst*4];
    #pragma unroll
    for (int h = 0; h < 4; ++h) a[h] = (a[h] > 0.f) ? a[h] : 0.2f*a[h];
    int pos = atomicAdd(&cur[dst], 1);
    csr_src[pos] = src;
    *(f4*)&csr_alpha[pos*4] = a;
}

// ---------------- segment softmax + aggregate: one wave per node ----------------
__global__ __launch_bounds__(256) void aggregate_kernel(const int* __restrict__ offs,
        const int* __restrict__ deg, const int* __restrict__ csr_src,
        const float* __restrict__ csr_alpha, const unsigned short* __restrict__ xt,
        const float* __restrict__ gat_bias, unsigned short* __restrict__ spat){
    int n = blockIdx.x*4 + (threadIdx.x >> 6);
    int lane = threadIdx.x & 63;
    int start = offs[n], d = deg[n];
    f4 mv = {-1e30f, -1e30f, -1e30f, -1e30f};
    for (int i = lane; i < d; i += 64)
        mv = fmax4(mv, *(const f4*)&csr_alpha[(start+i)*4]);
    #pragma unroll
    for (int o = 1; o < 64; o <<= 1) {
        f4 t; t[0]=__shfl_xor(mv[0],o,64); t[1]=__shfl_xor(mv[1],o,64);
        t[2]=__shfl_xor(mv[2],o,64); t[3]=__shfl_xor(mv[3],o,64);
        mv = fmax4(mv, t);
    }
    f4 sv = {};
    for (int i = lane; i < d; i += 64) {
        f4 a = *(const f4*)&csr_alpha[(start+i)*4];
        sv[0] += __expf(a[0]-mv[0]); sv[1] += __expf(a[1]-mv[1]);
        sv[2] += __expf(a[2]-mv[2]); sv[3] += __expf(a[3]-mv[3]);
    }
    #pragma unroll
    for (int o = 1; o < 64; o <<= 1) {
        sv[0]+=__shfl_xor(sv[0],o,64); sv[1]+=__shfl_xor(sv[1],o,64);
        sv[2]+=__shfl_xor(sv[2],o,64); sv[3]+=__shfl_xor(sv[3],o,64);
    }
    int h = lane >> 4;
    float mh = (h==0)?mv[0]:(h==1)?mv[1]:(h==2)?mv[2]:mv[3];
    float sh = (h==0)?sv[0]:(h==1)?sv[1]:(h==2)?sv[2]:sv[3];
    f4 accv = {};
    for (int base = 0; base < d; base += 64) {
        int cnt = min(64, d - base);
        int srcl = (base + lane < d) ? csr_src[start+base+lane] : 0;
        for (int i = 0; i < cnt; ++i) {
            int srcn = __shfl(srcl, i, 64);
            float av = csr_alpha[(start+base+i)*4 + h];
            float ew = __expf(av - mh);
            us4 xv = *(const us4*)&xt[srcn*256 + lane*4];
            accv[0] += ew * bf2f(xv[0]);
            accv[1] += ew * bf2f(xv[1]);
            accv[2] += ew * bf2f(xv[2]);
            accv[3] += ew * bf2f(xv[3]);
        }
    }
    float invs = 1.f / (sh + 1e-16f);
    f4 gb = *(const f4*)&gat_bias[lane*4];
    accv = accv * invs + gb;
    us4 o4; o4[0]=f2bf(accv[0]); o4[1]=f2bf(accv[1]); o4[2]=f2bf(accv[2]); o4[3]=f2bf(accv[3]);
    *(us4*)&spat[n*256 + lane*4] = o4;
}

// ---------------- LSTM layer: global_load_lds staging + XOR-swizzled LDS (T2/rule#21) ----------------
// LDS tiles linear [rows][64] bf16 (128B rows). LDS(row, bcol) holds global(row, bcol ^ ((row&7)<<4)):
// DMA writes linearly (base + lane*16); the inverse swizzle is applied to the per-lane GLOBAL source;
// ds_read applies the same XOR. Per 16-lane phase the 8 16B slots are each hit exactly twice -> 2-way
// aliasing = free (m136).
__global__ __launch_bounds__(256) void lstm_kernel(const unsigned short* __restrict__ A,
        const unsigned short* __restrict__ Bp, const float* __restrict__ bias,
        float* __restrict__ hs_out, float* __restrict__ cs_out, unsigned short* __restrict__ hnext){
    __shared__ unsigned short As[64*64];    // 8 KB
    __shared__ unsigned short Bs[192*64];   // 24 KB
    const int tid = threadIdx.x;
    const int bm = blockIdx.x, jb = blockIdx.y;
    const int lane = tid & 63, w = tid >> 6;
    const int nl = lane & 15, q = lane >> 4;
    const int rsub = lane >> 3, csub = lane & 7;
    const int swz = ((csub ^ rsub) << 4);   // byte offset of this lane's 16B block within a 128B row
    f4 acc[4][3] = {};
    // per-lane global base addresses (row = +rsub, col-block pre-swizzled)
    const char* Ab = (const char*)A + ((size_t)(bm*64 + rsub))*512 + swz;        // A row = 512B
    const char* Bb = (const char*)(Bp + (size_t)jb*192*256) + (size_t)rsub*512 + swz;
    for (int kc = 0; kc < 256; kc += 64) {
        // wave w stages: A insts t=2w..2w+1 (rows t*8..t*8+7), B insts t=6w..6w+5
        #pragma unroll
        for (int i = 0; i < 2; ++i) {
            int t = 2*w + i;
            gl_lds16(Ab + (size_t)t*4096 + kc*2, (char*)As + t*1024);
        }
        #pragma unroll
        for (int i = 0; i < 6; ++i) {
            int t = 6*w + i;
            gl_lds16(Bb + (size_t)t*4096 + kc*2, (char*)Bs + t*1024);
        }
        __syncthreads();   // compiler emits s_waitcnt vmcnt(0) before s_barrier -> DMA complete
        #pragma unroll
        for (int kk = 0; kk < 64; kk += 32) {
            const int cswz = (kk*2 + q*16) ^ ((nl & 7) << 4);
            bf16x8 a[4], b[3];
            #pragma unroll
            for (int mt = 0; mt < 4; ++mt)
                a[mt] = *(const bf16x8*)((const char*)As + (mt*16 + nl)*128 + cswz);
            #pragma unroll
            for (int gt = 0; gt < 3; ++gt)
                b[gt] = *(const bf16x8*)((const char*)Bs + (w*48 + gt*16 + nl)*128 + cswz);
            #pragma unroll
            for (int mt = 0; mt < 4; ++mt)
                #pragma unroll
                for (int gt = 0; gt < 3; ++gt)
                    acc[mt][gt] = __builtin_amdgcn_mfma_f32_16x16x32_bf16(a[mt], b[gt], acc[mt][gt], 0, 0, 0);
        }
        __syncthreads();
    }
    const int j = jb*64 + w*16 + nl;
    const float bi = bias[jb*192 + w*48 +  0 + nl];
    const float bg = bias[jb*192 + w*48 + 16 + nl];
    const float bo = bias[jb*192 + w*48 + 32 + nl];
    #pragma unroll
    for (int mt = 0; mt < 4; ++mt)
        #pragma unroll
        for (int r = 0; r < 4; ++r) {
            int m = bm*64 + mt*16 + q*4 + r;
            float iv = acc[mt][0][r] + bi;
            float gv = acc[mt][1][r] + bg;
            float ov = acc[mt][2][r] + bo;
            float c = sigf(iv) * tanhfast(gv);
            float hh = sigf(ov) * tanhfast(c);
            cs_out[m*256 + j] = c;
            hs_out[m*256 + j] = hh;
            if (hnext) hnext[m*256 + j] = f2bf(hh);
        }
}

// ---------------- LayerNorm ----------------
__global__ __launch_bounds__(256) void ln_kernel(const float* __restrict__ hin,
        const float* __restrict__ g, const float* __restrict__ b, float* __restrict__ out){
    int n = blockIdx.x*4 + (threadIdx.x >> 6);
    int lane = threadIdx.x & 63;
    f4 v = *(const f4*)&hin[n*256 + lane*4];
    float s = v[0]+v[1]+v[2]+v[3];
    float ss = v[0]*v[0]+v[1]*v[1]+v[2]*v[2]+v[3]*v[3];
    #pragma unroll
    for (int o = 1; o < 64; o <<= 1) { s += __shfl_xor(s,o,64); ss += __shfl_xor(ss,o,64); }
    float mu = s * (1.f/256.f);
    float var = ss * (1.f/256.f) - mu*mu;
    float rstd = rsqrtf(var + 1e-5f);
    f4 gg = *(const f4*)&g[lane*4], bb = *(const f4*)&b[lane*4];
    f4 o4 = (v - mu) * rstd * gg + bb;
    *(f4*)&out[n*256 + lane*4] = o4;
}

// ---------------- host ----------------
static inline char* carve(char*& p, size_t bytes){
    char* r = p; p += (bytes + 255) & ~(size_t)255; return r;
}

extern "C" void kernel_launch(void* const* d_in, const int* in_sizes, int n_in,
                              void* d_out, int out_size, void* d_ws, size_t ws_size,
                              hipStream_t stream){
    const float* x         = (const float*)d_in[0];
    const int*   ei        = (const int*)  d_in[1];
    const float* edge_attr = (const float*)d_in[2];
    const float* lin_w     = (const float*)d_in[3];
    const float* att_src   = (const float*)d_in[4];
    const float* att_dst   = (const float*)d_in[5];
    const float* lin_edge_w= (const float*)d_in[6];
    const float* att_edge  = (const float*)d_in[7];
    const float* gat_bias  = (const float*)d_in[8];
    const float* w_ih      = (const float*)d_in[9];
    const float* b_ih      = (const float*)d_in[11];
    const float* b_hh      = (const float*)d_in[12];
    const float* ln_g      = (const float*)d_in[13];
    const float* ln_b      = (const float*)d_in[14];

    float* out = (float*)d_out;
    float* hs_base = out + 10240000;          // [3][40000][256]
    float* cs_base = out + 40960000;          // [3][40000][256]

    // scratch aliased into d_out (liveness verified: each region is dead before
    // the kernel that writes its final contents runs)
    unsigned short* xt   = (unsigned short*)(out + 0);          // dead after aggregate
    float* esc           = out + 10240000;                       // dead before layer0 writes hs[0]
    int*   csr_src       = (int*)(out + 40960000);               // dead before layer0 writes cs[0]
    float* csr_alpha     = out + 41640000;                       // ditto
    unsigned short* spat = (unsigned short*)(out + 51200000);    // in cs[1], dead before layer1
    unsigned short* h0   = (unsigned short*)(out + 61440000);    // in cs[2], dead before layer2
    unsigned short* h1   = (unsigned short*)(out + 0);           // reuse xt region

    char* p = (char*)d_ws;
    float* W2          = (float*)carve(p, 64*4);
    float* s_src       = (float*)carve(p, (size_t)BN_*4*4);
    float* s_dst       = (float*)carve(p, (size_t)BN_*4*4);
    unsigned short* lwT= (unsigned short*)carve(p, 32768*2);
    unsigned short* Bp = (unsigned short*)carve(p, 589824*2);
    float* biasP       = (float*)carve(p, 2304*4);
    int* deg           = (int*)carve(p, BN_*4);
    int* inc           = (int*)carve(p, 157*256*4);
    int* bsum          = (int*)carve(p, 256*4);
    int* bpre          = (int*)carve(p, 256*4);
    int* offs          = (int*)carve(p, BN_*4);
    int* cur           = (int*)carve(p, BN_*4);

    hipMemsetAsync(deg, 0, BN_*4, stream);
    w2_kernel<<<1, 64, 0, stream>>>(lin_edge_w, att_edge, W2);
    pack_linwT_kernel<<<128, 256, 0, stream>>>(lin_w, lwT);
    pack_lstmw_kernel<<<2304, 256, 0, stream>>>(w_ih, Bp);
    pack_bias_kernel<<<9, 256, 0, stream>>>(b_ih, b_hh, biasP);

    gemm1_kernel<<<dim3(625, 4), 256, 0, stream>>>(x, lwT, xt);
    scores_kernel<<<10000, 256, 0, stream>>>(xt, att_src, att_dst, s_src, s_dst);
    eascore_kernel<<<1250, 256, 0, stream>>>(edge_attr, W2, esc);

    deghist_kernel<<<2657, 256, 0, stream>>>(ei, deg);
    scan1_kernel<<<157, 256, 0, stream>>>(deg, inc, bsum);
    scan2_kernel<<<1, 256, 0, stream>>>(bsum, bpre, 157);
    scan3_kernel<<<157, 256, 0, stream>>>(inc, deg, bpre, offs, cur);
    scatter_kernel<<<2657, 256, 0, stream>>>(ei, s_src, s_dst, esc, cur, csr_src, csr_alpha);
    aggregate_kernel<<<10000, 256, 0, stream>>>(offs, deg, csr_src, csr_alpha, xt, gat_bias, spat);

    lstm_kernel<<<dim3(625, 4), 256, 0, stream>>>(spat, Bp,          biasP,        hs_base,            cs_base,            h0);
    lstm_kernel<<<dim3(625, 4), 256, 0, stream>>>(h0,   Bp + 196608, biasP + 768,  hs_base + 10240000, cs_base + 10240000, h1);
    lstm_kernel<<<dim3(625, 4), 256, 0, stream>>>(h1,   Bp + 393216, biasP + 1536, hs_base + 20480000, cs_base + 20480000, (unsigned short*)nullptr);

    ln_kernel<<<10000, 256, 0, stream>>>(hs_base + 20480000, ln_g, ln_b, out);
}